// Round 2
// baseline (312.550 us; speedup 1.0000x reference)
//
#include <hip/hip_runtime.h>

// PadWithin: out[b,c,2i,2j] = feats[b,c,i,j], all other entries zero.
// feats: (16,64,128,128) fp32 -> out: (16,64,256,256) fp32.
// Pure streaming memory movement: 64 MiB read + 256 MiB write (full output
// must be written — harness re-poisons d_out with 0xAA each call).
// Mandatory traffic 335.5 MB @ ~6.3 TB/s achievable => ~53 us roofline.
//
// Structure: one wave per input row ("row-pair" of the output). Each output
// row-pair (rows 2i, 2i+1) is a contiguous 2 KiB span:
//   lane stores expanded float4 at [lane], zero float4 at [64+lane].
// Each wave owns 16 CONSECUTIVE row-pairs (32 KiB contiguous output,
// 8 KiB contiguous input) -> good DRAM page locality per CU, small address
// deltas. 2048 blocks x 256 thr = 8192 waves x 16 pairs = 131072 = exact.
// NOTE: no nontemporal hints — round-1 A/B showed them costing ~10 us
// (nt stores forfeit L2 write combining on gfx950).

#define IN_W   128
#define PAIRS  (16 * 64 * 128)   // B*C*IN_H input rows == output row-pairs
#define PAIRS_PER_WAVE 16

typedef float f2 __attribute__((ext_vector_type(2)));
typedef float f4 __attribute__((ext_vector_type(4)));

__global__ __launch_bounds__(256) void pad_within_kernel(
    const float* __restrict__ in, float* __restrict__ out) {
    const unsigned lane = threadIdx.x & 63u;
    const unsigned wid  = (blockIdx.x * blockDim.x + threadIdx.x) >> 6;

    const unsigned p0 = wid * PAIRS_PER_WAVE;   // first input row for this wave

    const f2* irow  = (const f2*)(in  + (size_t)p0 * IN_W) + lane;   // float2/row
    f4*       opair = (f4*)      (out + (size_t)p0 * 512)  + lane;   // 128 f4/pair

    const f4 zero = {0.f, 0.f, 0.f, 0.f};

    #pragma unroll 4
    for (unsigned k = 0; k < PAIRS_PER_WAVE; ++k) {
        f2 x = irow[(size_t)k * 64];            // 512 B/wave, coalesced
        f4 val = {x.x, 0.f, x.y, 0.f};
        opair[(size_t)k * 128]       = val;     // even output row
        opair[(size_t)k * 128 + 64]  = zero;    // odd output row (all zeros)
    }
}

extern "C" void kernel_launch(void* const* d_in, const int* in_sizes, int n_in,
                              void* d_out, int out_size, void* d_ws, size_t ws_size,
                              hipStream_t stream) {
    const float* feats = (const float*)d_in[0];
    float* out = (float*)d_out;
    dim3 block(256);
    dim3 grid(2048);   // 8192 waves * 16 pairs = 131072 pairs, no tail
    pad_within_kernel<<<grid, block, 0, stream>>>(feats, out);
}